// Round 9
// baseline (213.095 us; speedup 1.0000x reference)
//
#include <hip/hip_runtime.h>
#include <hip/hip_bf16.h>
#include <math.h>

#define B_ 16
#define C_ 64
#define N_ 4096   // 64*64 pixels
#define M_ 1024   // 32*32 pooled keys
#define LOG2E 1.44269504088896f

typedef __attribute__((ext_vector_type(8))) short v8s;   // 8 bf16 (4 VGPRs)
typedef __attribute__((ext_vector_type(4))) short v4s;   // 4 bf16 (2 VGPRs)
typedef __attribute__((ext_vector_type(4))) float v4f;   // 4 fp32 acc

__device__ inline float fast_exp2(float x) {
    return __builtin_amdgcn_exp2f(x);     // v_exp_f32: D = 2^S0
}

__device__ inline unsigned short f2bf(float f) {
    __hip_bfloat16 h = __float2bfloat16(f);
    return *(unsigned short*)&h;
}
__device__ inline unsigned pack2bf(float a, float b) {
    return (unsigned)f2bf(a) | ((unsigned)f2bf(b) << 16);
}
__device__ inline v8s cvt8(float4 a, float4 b) {
    union { v8s v; unsigned u[4]; } r;
    r.u[0] = pack2bf(a.x, a.y);
    r.u[1] = pack2bf(a.z, a.w);
    r.u[2] = pack2bf(b.x, b.y);
    r.u[3] = pack2bf(b.z, b.w);
    return r.v;
}
__device__ inline v4s cvt4(float4 a) {
    union { v4s v; unsigned u[2]; } r;
    r.u[0] = pack2bf(a.x, a.y);
    r.u[1] = pack2bf(a.z, a.w);
    return r.v;
}

// K=16 bf16 MFMA: A[m=l15][k=l4*4+j], B[k=l4*4+j][n=l15],
// C/D: col=l15, row=l4*4+reg (16x16-family layout).
__device__ inline v4f mfma16(v4s a, v4s b, v4f c) {
#if __has_builtin(__builtin_amdgcn_mfma_f32_16x16x16bf16_1k)
    return __builtin_amdgcn_mfma_f32_16x16x16bf16_1k(a, b, c, 0, 0, 0);
#else
    v4f d;
    asm("v_mfma_f32_16x16x16_bf16 %0, %1, %2, %3\n\ts_nop 7\n\ts_nop 7"
        : "=&v"(d) : "v"(a), "v"(b), "v"(c));
    return d;
#endif
}

// ---------------------------------------------------------------------------
// Kernel 1: R4 conv (best measured) + ONE change: theta is scaled by log2(e)
// at pack time, so attn computes exp(S) as exp2(S') = single v_exp_f32.
// ---------------------------------------------------------------------------
#define SP2 66   // sPool row stride (floats)

__global__ __launch_bounds__(256, 2) void conv_pool_k(
    const float* __restrict__ x,
    const float* __restrict__ Wt, const float* __restrict__ bt,
    const float* __restrict__ Wp, const float* __restrict__ bp,
    const float* __restrict__ Wg, const float* __restrict__ bg,
    unsigned short* __restrict__ thetaT,
    unsigned short* __restrict__ phiT,
    unsigned short* __restrict__ gcm)
{
    __shared__ float sPool[80 * SP2];   // 40 ch x 2 rows = 80 rows, 21.1 KB

    const int tid  = threadIdx.x;
    const int lane = tid & 63;
    const int wid  = tid >> 6;
    const int l15  = lane & 15;
    const int l4   = lane >> 4;

    const int b  = blockIdx.x >> 5;
    const int y0 = (blockIdx.x & 31) << 1;   // first of 2 image rows
    const int y  = y0 + (wid >> 1);          // this wave's row
    const int xh = (wid & 1) * 32;           // this wave's half-row

    // --- A-fragments: weights, 3 m-tiles x 2 k-halves (bf16, loaded once)
    const float* row0 = (l15 < 8) ? (Wt + l15 * 64) : (Wp + (l15 - 8) * 64);
    const float* row1 = Wg + l15 * 64;
    const float* row2 = Wg + (16 + l15) * 64;
    v8s afrag[3][2];
    #pragma unroll
    for (int kh = 0; kh < 2; ++kh) {
        const int c0 = kh * 32 + l4 * 8;
        afrag[0][kh] = cvt8(*(const float4*)(row0 + c0), *(const float4*)(row0 + c0 + 4));
        afrag[1][kh] = cvt8(*(const float4*)(row1 + c0), *(const float4*)(row1 + c0 + 4));
        afrag[2][kh] = cvt8(*(const float4*)(row2 + c0), *(const float4*)(row2 + c0 + 4));
    }

    // --- accumulators init = bias (C-layout: row o = l4*4+r)
    v4f acc[2][3];
    {
        float bv[3][4];
        #pragma unroll
        for (int r = 0; r < 4; ++r) {
            const int o = l4 * 4 + r;               // 0..15
            bv[0][r] = (o < 8) ? bt[o] : bp[o - 8];
            bv[1][r] = bg[o];
            bv[2][r] = bg[16 + o];
        }
        #pragma unroll
        for (int nt = 0; nt < 2; ++nt)
            #pragma unroll
            for (int t = 0; t < 3; ++t) {
                v4f a; a[0] = bv[t][0]; a[1] = bv[t][1];
                a[2] = bv[t][2]; a[3] = bv[t][3];
                acc[nt][t] = a;
            }
    }

    // --- main GEMM: 2 n-tiles x 2 k-halves x 3 m-tiles
    const float* xb = x + (size_t)b * C_ * N_ + y * 64;
    #pragma unroll
    for (int nt = 0; nt < 2; ++nt) {
        const int n0 = xh + nt * 16 + l15;
        #pragma unroll
        for (int kh = 0; kh < 2; ++kh) {
            const int cb = kh * 32 + l4 * 8;
            float f[8];
            #pragma unroll
            for (int j = 0; j < 8; ++j) f[j] = xb[(size_t)(cb + j) * N_ + n0];
            union { v8s v; unsigned u[4]; } bf;
            #pragma unroll
            for (int j = 0; j < 4; ++j) bf.u[j] = pack2bf(f[2*j], f[2*j+1]);
            #pragma unroll
            for (int t = 0; t < 3; ++t)
                acc[nt][t] = __builtin_amdgcn_mfma_f32_16x16x32_bf16(
                    afrag[t][kh], bf.v, acc[nt][t], 0, 0, 0);
        }
    }

    // --- theta (scaled by log2e): from C-regs, rows 0..7 of m-tile 0
    #pragma unroll
    for (int nt = 0; nt < 2; ++nt) {
        if (l4 < 2) {
            const int n = y * 64 + xh + nt * 16 + l15;
            const unsigned lo = pack2bf(acc[nt][0][0] * LOG2E, acc[nt][0][1] * LOG2E);
            const unsigned hi = pack2bf(acc[nt][0][2] * LOG2E, acc[nt][0][3] * LOG2E);
            *(uint2*)(thetaT + ((size_t)b * N_ + n) * 8 + l4 * 4) = make_uint2(lo, hi);
        }
    }

    // --- stage phi/g to LDS for pooling: row index = ch*2 + (image row in pair)
    {
        const int rr = wid >> 1;   // 0/1: which row of the pair
        #pragma unroll
        for (int nt = 0; nt < 2; ++nt) {
            const int px = xh + nt * 16 + l15;      // 0..63
            if (l4 >= 2) {                          // phi: ch = (l4-2)*4 + r
                #pragma unroll
                for (int r = 0; r < 4; ++r)
                    sPool[(((l4 - 2) * 4 + r) * 2 + rr) * SP2 + px] = acc[nt][0][r];
            }
            #pragma unroll
            for (int r = 0; r < 4; ++r) {
                sPool[((8  + l4 * 4 + r) * 2 + rr) * SP2 + px] = acc[nt][1][r];
                sPool[((24 + l4 * 4 + r) * 2 + rr) * SP2 + px] = acc[nt][2][r];
            }
        }
    }
    __syncthreads();

    // --- 2x2 maxpool + store: 40 ch x 32 pooled px per block
    {
        const int pc  = tid & 31;          // pooled col
        const int grp = tid >> 5;          // 8 groups x 5 channels
        const int mg  = (y0 >> 1) * 32 + pc;
        #pragma unroll
        for (int i = 0; i < 5; ++i) {
            const int ch = grp * 5 + i;
            const float* s0 = sPool + (ch * 2 + 0) * SP2 + pc * 2;
            const float* s1 = sPool + (ch * 2 + 1) * SP2 + pc * 2;
            const float v = fmaxf(fmaxf(s0[0], s0[1]), fmaxf(s1[0], s1[1]));
            if (ch < 8) phiT[((size_t)b * M_ + mg) * 8 + ch] = f2bf(v);
            else        gcm[((size_t)(b * 32 + ch - 8)) * M_ + mg] = f2bf(v);
        }
    }
}

// ---------------------------------------------------------------------------
// Kernel 2 (round 12 resubmit): zero-LDS, zero-barrier, NAMED-REGISTER
// pipelined attn.  R3->R4 (occupancy 2x: null) and R7 (waves 2x: -7%)
// exclude latency-coverage; the barrier lockstep is the serializer.  R5's
// design with the spill bug fixed: NO arrays (nothing can go to scratch),
// named fragment scalars, full unroll, explicit 2-chunk-ahead prefetch.
// Operands L2-warm (conv just wrote phi/g 1.3MB; theta 1MB).  4 free-
// running waves/SIMD, no __syncthreads anywhere.
// exp(S) -> exp2(S') via __builtin_amdgcn_exp2f since theta carries log2e.
// ---------------------------------------------------------------------------
__global__ __launch_bounds__(256, 4) void attn_k(
    const float* __restrict__ x,
    const unsigned short* __restrict__ thetaT,
    const unsigned short* __restrict__ phiT,
    const unsigned short* __restrict__ gcm,
    const float* __restrict__ Wo, const float* __restrict__ bo,
    const float* __restrict__ gammap,
    float* __restrict__ out)
{
    const int tid  = threadIdx.x;
    const int lane = tid & 63;
    const int wid  = tid >> 6;
    const int l15  = lane & 15;
    const int l4   = lane >> 4;

    const int b  = blockIdx.x >> 6;
    const int qw = ((blockIdx.x & 63) << 6) + wid * 16;   // 16 queries/wave

    // --- theta B-frag (K=16: k=ch l4*4+j, real for l4<2, zero else)
    v4s bth; { v4s z = {}; bth = z; }
    if (l4 < 2)
        bth = *(const v4s*)(thetaT + ((size_t)b * N_ + qw + l15) * 8 + l4 * 4);

    // --- per-lane base pointers (chunk kk: phi +kk*128 shorts, g +kk*16)
    const unsigned short* phB = phiT + (size_t)b * M_ * 8 + l15 * 8 + (l4 & 1) * 4;
    const unsigned short* g0B = gcm + ((size_t)(b * 32) + l15) * M_ + l4 * 4;
    const unsigned short* g1B = g0B + 16 * M_;

    // --- accumulators (even/odd split breaks the PV dependency chain)
    v4f accA0, accA1, accB0, accB1;
    { v4f z = {}; accA0 = z; accA1 = z; accB0 = z; accB1 = z; }
    float lsum = 0.f;
    const v4f zf = {};

    // --- NAMED 2-chunk-ahead pipeline (no arrays -> no scratch, rule #20)
    v4s pA, gA0, gA1;     // fragments for even chunk in flight
    v4s pB, gB0, gB1;     // fragments for odd chunk in flight

    pA  = *(const v4s*)(phB + 0 * 128);
    gA0 = *(const v4s*)(g0B + 0 * 16);
    gA1 = *(const v4s*)(g1B + 0 * 16);
    pB  = *(const v4s*)(phB + 1 * 128);
    gB0 = *(const v4s*)(g0B + 1 * 16);
    gB1 = *(const v4s*)(g1B + 1 * 16);

    #pragma unroll
    for (int kk = 0; kk < 64; kk += 2) {
        // ---- compute even chunk (kk) from A-regs
        {
            v4f s = mfma16(pA, bth, zf);
            const float e0 = fast_exp2(s[0]), e1 = fast_exp2(s[1]);
            const float e2 = fast_exp2(s[2]), e3 = fast_exp2(s[3]);
            lsum += (e0 + e1) + (e2 + e3);
            union { v4s v; unsigned u[2]; } p;
            p.u[0] = pack2bf(e0, e1);
            p.u[1] = pack2bf(e2, e3);
            accA0 = mfma16(gA0, p.v, accA0);
            accA1 = mfma16(gA1, p.v, accA1);
        }
        // ---- refill A with chunk kk+2 (consumed above; static offsets)
        if (kk + 2 < 64) {
            pA  = *(const v4s*)(phB + (kk + 2) * 128);
            gA0 = *(const v4s*)(g0B + (kk + 2) * 16);
            gA1 = *(const v4s*)(g1B + (kk + 2) * 16);
        }
        // ---- compute odd chunk (kk+1) from B-regs
        {
            v4f s = mfma16(pB, bth, zf);
            const float e0 = fast_exp2(s[0]), e1 = fast_exp2(s[1]);
            const float e2 = fast_exp2(s[2]), e3 = fast_exp2(s[3]);
            lsum += (e0 + e1) + (e2 + e3);
            union { v4s v; unsigned u[2]; } p;
            p.u[0] = pack2bf(e0, e1);
            p.u[1] = pack2bf(e2, e3);
            accB0 = mfma16(gB0, p.v, accB0);
            accB1 = mfma16(gB1, p.v, accB1);
        }
        // ---- refill B with chunk kk+3
        if (kk + 3 < 64) {
            pB  = *(const v4s*)(phB + (kk + 3) * 128);
            gB0 = *(const v4s*)(g0B + (kk + 3) * 16);
            gB1 = *(const v4s*)(g1B + (kk + 3) * 16);
        }
    }

    v4f acc0 = accA0 + accB0;                // O[c=l4*4+r][q=l15], c-tile 0
    v4f acc1 = accA1 + accB1;                // c-tile 1 (c+16)

    // --- softmax denominator: sum over the 4 l4-groups sharing query l15
    float v = lsum;
    v += __shfl_xor(v, 16);
    v += __shfl_xor(v, 32);
    const float rl = 1.0f / v;

    // --- normalize + pack O -> B-frags of the output-conv MFMA (k=c=l4*4+j)
    v4s pO0, pO1;
    {
        union { v4s v; unsigned u[2]; } p;
        p.u[0] = pack2bf(acc0[0] * rl, acc0[1] * rl);
        p.u[1] = pack2bf(acc0[2] * rl, acc0[3] * rl);
        pO0 = p.v;
        p.u[0] = pack2bf(acc1[0] * rl, acc1[1] * rl);
        p.u[1] = pack2bf(acc1[2] * rl, acc1[3] * rl);
        pO1 = p.v;
    }

    // --- output conv via 8 K=16 MFMAs + residual.  Wo/bo loaded here
    // (off the main loop's register budget).  D[m=oc][n=q], bias in C-init.
    const float gamma = *gammap;
    const size_t colq = qw + l15;
    #pragma unroll
    for (int mt = 0; mt < 4; ++mt) {
        const int oc0 = mt * 16 + l4 * 4;
        const float4 w0 = *(const float4*)(Wo + (mt * 16 + l15) * 32 + l4 * 4);
        const float4 w1 = *(const float4*)(Wo + (mt * 16 + l15) * 32 + 16 + l4 * 4);
        const float4 bo4 = *(const float4*)(bo + oc0);
        v4f c; c[0] = bo4.x; c[1] = bo4.y; c[2] = bo4.z; c[3] = bo4.w;
        c = mfma16(cvt4(w0), pO0, c);
        c = mfma16(cvt4(w1), pO1, c);
        const float* xr   = x   + ((size_t)(b * 64 + oc0)) * N_ + colq;
        float*       orow = out + ((size_t)(b * 64 + oc0)) * N_ + colq;
        #pragma unroll
        for (int r = 0; r < 4; ++r)
            orow[(size_t)r * N_] = gamma * c[r] + xr[(size_t)r * N_];
    }
}

// ---------------------------------------------------------------------------
extern "C" void kernel_launch(void* const* d_in, const int* in_sizes, int n_in,
                              void* d_out, int out_size, void* d_ws, size_t ws_size,
                              hipStream_t stream) {
    const float* x  = (const float*)d_in[0];
    const float* Wt = (const float*)d_in[1];
    const float* bt = (const float*)d_in[2];
    const float* Wp = (const float*)d_in[3];
    const float* bp = (const float*)d_in[4];
    const float* Wg = (const float*)d_in[5];
    const float* bg = (const float*)d_in[6];
    const float* Wo = (const float*)d_in[7];
    const float* bo = (const float*)d_in[8];
    const float* gm = (const float*)d_in[9];
    float* out = (float*)d_out;

    // workspace (bf16): thetaT [16][4096][8] | phiT [16][1024][8] | gcm [16][32][1024]
    unsigned short* thetaT = (unsigned short*)d_ws;
    unsigned short* phiT   = thetaT + (size_t)B_ * N_ * 8;
    unsigned short* gcm    = phiT   + (size_t)B_ * M_ * 8;

    hipLaunchKernelGGL(conv_pool_k, dim3(512), dim3(256), 0, stream,
                       x, Wt, bt, Wp, bp, Wg, bg, thetaT, phiT, gcm);
    hipLaunchKernelGGL(attn_k, dim3(1024), dim3(256), 0, stream,
                       x, thetaT, phiT, gcm, Wo, bo, gm, out);
}